// Round 1
// baseline (149.370 us; speedup 1.0000x reference)
//
#include <hip/hip_runtime.h>
#include <float.h>

// Chamfer distance: loss = mean_n min_m d(x_n, r_m) + mean_m min_n d(r_m, x_n)
// d computed via ||t||^2 - 2 q.t + ||q||^2 (same expansion as the JAX ref).
// B=32, N=M=4096, C=3, fp32 in / fp32 scalar out.

#define TM   2048   // target points staged per LDS tile (32 KiB as float4)
#define QPT  2      // query points per thread
#define BLK  256

struct __align__(16) F4 { float x, y, z, s; };

__global__ __launch_bounds__(BLK)
void chamfer_kernel(const float* __restrict__ x,
                    const float* __restrict__ recon,
                    float* __restrict__ out,
                    int B, int N, int M, float scale)
{
    // blockIdx.y == 0 : query = x, target = recon  (cost_p2_p1)
    // blockIdx.y == 1 : query = recon, target = x  (cost_p1_p2)
    const float* q = (blockIdx.y == 0) ? x : recon;
    const float* t = (blockIdx.y == 0) ? recon : x;
    const int Nq = N;            // queries per batch (N == M here)
    const int Mt = M;

    const int qpb    = BLK * QPT;            // 512 queries per block
    const int chunks = Nq / qpb;             // 8
    const int b      = blockIdx.x / chunks;
    const int chunk  = blockIdx.x % chunks;
    const int tid    = threadIdx.x;

    __shared__ F4 lds[TM];
    __shared__ float red[BLK / 64];

    // Load this thread's query points; precompute -2*q and ||q||^2.
    float nqx[QPT], nqy[QPT], nqz[QPT], q2[QPT], mn[QPT];
    #pragma unroll
    for (int i = 0; i < QPT; ++i) {
        int n = chunk * qpb + i * BLK + tid;
        const float* qp = q + ((size_t)b * Nq + n) * 3;
        float a0 = qp[0], a1 = qp[1], a2 = qp[2];
        nqx[i] = -2.0f * a0; nqy[i] = -2.0f * a1; nqz[i] = -2.0f * a2;
        q2[i]  = a0 * a0 + a1 * a1 + a2 * a2;
        mn[i]  = FLT_MAX;
    }

    const float* tb = t + (size_t)b * Mt * 3;
    for (int m0 = 0; m0 < Mt; m0 += TM) {
        __syncthreads();   // previous tile fully consumed before overwrite
        // Stage TM raw points (3 floats each), coalesced flat copy.
        const float* src = tb + (size_t)m0 * 3;
        for (int e = tid; e < TM * 3; e += BLK) {
            int m = e / 3, c = e - 3 * m;
            ((float*)&lds[m])[c] = src[e];
        }
        __syncthreads();
        // Fill s = ||t||^2.
        for (int m = tid; m < TM; m += BLK) {
            F4 p = lds[m];
            lds[m].s = p.x * p.x + p.y * p.y + p.z * p.z;
        }
        __syncthreads();
        // Main loop: uniform-address ds_read_b128 broadcast + 4 VALU/pair.
        #pragma unroll 8
        for (int m = 0; m < TM; ++m) {
            F4 p = lds[m];
            #pragma unroll
            for (int i = 0; i < QPT; ++i) {
                float d = fmaf(nqx[i], p.x, p.s);
                d = fmaf(nqy[i], p.y, d);
                d = fmaf(nqz[i], p.z, d);
                mn[i] = fminf(mn[i], d);
            }
        }
    }

    // Per-thread contribution: sum of (min + ||q||^2) over its queries.
    float v = 0.0f;
    #pragma unroll
    for (int i = 0; i < QPT; ++i) v += mn[i] + q2[i];

    // Wave64 shuffle reduce, then cross-wave via LDS, then one atomic.
    #pragma unroll
    for (int off = 32; off > 0; off >>= 1)
        v += __shfl_down(v, off, 64);
    if ((tid & 63) == 0) red[tid >> 6] = v;
    __syncthreads();
    if (tid == 0) {
        float s = 0.0f;
        #pragma unroll
        for (int w = 0; w < BLK / 64; ++w) s += red[w];
        atomicAdd(out, s * scale);
    }
}

extern "C" void kernel_launch(void* const* d_in, const int* in_sizes, int n_in,
                              void* d_out, int out_size, void* d_ws, size_t ws_size,
                              hipStream_t stream) {
    const float* x     = (const float*)d_in[0];
    const float* recon = (const float*)d_in[1];
    float* out = (float*)d_out;

    const int B = 32, N = 4096, M = 4096;
    const float scale = 1.0f / ((float)B * (float)N);  // N == M

    hipMemsetAsync(out, 0, sizeof(float), stream);

    dim3 grid(B * (N / (BLK * QPT)), 2);   // (256, 2)
    chamfer_kernel<<<grid, BLK, 0, stream>>>(x, recon, out, B, N, M, scale);
}